// Round 6
// baseline (1671.968 us; speedup 1.0000x reference)
//
#include <hip/hip_runtime.h>
#include <hip/hip_bf16.h>

#define D 128

// ---------------- degree histogram ----------------
__global__ void k_degree(const int* __restrict__ dst, int E, int* __restrict__ degi) {
    int i = blockIdx.x * blockDim.x + threadIdx.x;
    if (i < E) atomicAdd(&degi[dst[i]], 1);
}

__global__ void k_dinv(const int* __restrict__ degi, float* __restrict__ dinv, int N) {
    int i = blockIdx.x * blockDim.x + threadIdx.x;
    if (i < N) dinv[i] = rsqrtf((float)degi[i] + 1.0f);
}

// ---------------- single-block exclusive scan over degrees ----------------
__global__ __launch_bounds__(1024) void k_scan(const int* __restrict__ degi,
                                               int* __restrict__ offsets,
                                               int* __restrict__ cursor, int N) {
    __shared__ int sums[1024];
    int t = threadIdx.x;
    int chunk = (N + 1023) >> 10;
    int beg = t * chunk;
    int end = min(beg + chunk, N);
    int s = 0;
    for (int i = beg; i < end; ++i) s += degi[i];
    sums[t] = s;
    __syncthreads();
    // Hillis-Steele inclusive scan over the 1024 partial sums
    for (int off = 1; off < 1024; off <<= 1) {
        int v = 0;
        if (t >= off) v = sums[t - off];
        __syncthreads();
        sums[t] += v;
        __syncthreads();
    }
    int base = sums[t] - s;  // exclusive prefix for this chunk
    int run = base;
    for (int i = beg; i < end; ++i) {
        offsets[i] = run;
        cursor[i] = run;
        run += degi[i];
    }
    if (end == N) offsets[N] = run;  // all qualifying threads write total E
}

// ---------------- CSR fill (order within a node nondeterministic; fp-assoc noise only) ----
__global__ void k_fill(const int* __restrict__ src, const int* __restrict__ dst, int E,
                       const float* __restrict__ dinv, int* __restrict__ cursor,
                       int* __restrict__ csr_src, float* __restrict__ csr_coef) {
    int i = blockIdx.x * blockDim.x + threadIdx.x;
    if (i < E) {
        int s = src[i], d = dst[i];
        int pos = atomicAdd(&cursor[d], 1);
        csr_src[pos] = s;
        csr_coef[pos] = dinv[s] * dinv[d];
    }
}

// ---------------- f32 GEMM: H[N,128] = X[N,128] @ W[128,128] ----------------
// block 256 threads = 64-row tile; x tile staged in LDS; W rows via L1 (coalesced 512B)
__global__ __launch_bounds__(256) void k_gemm(const float* __restrict__ X,
                                              const float* __restrict__ W,
                                              float* __restrict__ H, int N) {
    __shared__ float4 xs[64 * 32];
    int tid = threadIdx.x;
    int base = blockIdx.x * 64;
    const float4* X4 = (const float4*)X;
#pragma unroll
    for (int i = 0; i < 8; ++i) {
        int f4 = tid + i * 256;
        int row = base + (f4 >> 5);
        float4 v = make_float4(0.f, 0.f, 0.f, 0.f);
        if (row < N) v = X4[(size_t)base * 32 + f4];
        xs[f4] = v;
    }
    __syncthreads();

    int c4 = tid & 31;        // col group (4 cols)
    int r0 = (tid >> 5) * 8;  // first row in tile for this thread
    float4 acc[8];
#pragma unroll
    for (int i = 0; i < 8; ++i) acc[i] = make_float4(0.f, 0.f, 0.f, 0.f);

    const float4* W4 = (const float4*)W;
#pragma unroll 2
    for (int k4 = 0; k4 < 32; ++k4) {
        float4 w0 = W4[(k4 * 4 + 0) * 32 + c4];
        float4 w1 = W4[(k4 * 4 + 1) * 32 + c4];
        float4 w2 = W4[(k4 * 4 + 2) * 32 + c4];
        float4 w3 = W4[(k4 * 4 + 3) * 32 + c4];
#pragma unroll
        for (int i = 0; i < 8; ++i) {
            float4 xv = xs[(r0 + i) * 32 + k4];
            acc[i].x = fmaf(xv.x, w0.x, acc[i].x);
            acc[i].y = fmaf(xv.x, w0.y, acc[i].y);
            acc[i].z = fmaf(xv.x, w0.z, acc[i].z);
            acc[i].w = fmaf(xv.x, w0.w, acc[i].w);
            acc[i].x = fmaf(xv.y, w1.x, acc[i].x);
            acc[i].y = fmaf(xv.y, w1.y, acc[i].y);
            acc[i].z = fmaf(xv.y, w1.z, acc[i].z);
            acc[i].w = fmaf(xv.y, w1.w, acc[i].w);
            acc[i].x = fmaf(xv.z, w2.x, acc[i].x);
            acc[i].y = fmaf(xv.z, w2.y, acc[i].y);
            acc[i].z = fmaf(xv.z, w2.z, acc[i].z);
            acc[i].w = fmaf(xv.z, w2.w, acc[i].w);
            acc[i].x = fmaf(xv.w, w3.x, acc[i].x);
            acc[i].y = fmaf(xv.w, w3.y, acc[i].y);
            acc[i].z = fmaf(xv.w, w3.z, acc[i].z);
            acc[i].w = fmaf(xv.w, w3.w, acc[i].w);
        }
    }
#pragma unroll
    for (int i = 0; i < 8; ++i) {
        int row = base + r0 + i;
        if (row < N) *(float4*)&H[(size_t)row * D + c4 * 4] = acc[i];
    }
}

// ---------------- aggregation: out = relu(D^-1/2 (A+I) D^-1/2 H + b) ----------------
// 128 threads per node (one feature each); CSR neighbor loop, no atomics
__global__ __launch_bounds__(256) void k_agg(const float* __restrict__ H,
                                             const int* __restrict__ offsets,
                                             const int* __restrict__ csr_src,
                                             const float* __restrict__ csr_coef,
                                             const float* __restrict__ dinv,
                                             const float* __restrict__ bias,
                                             float* __restrict__ Out, int N) {
    int n = blockIdx.x * 2 + (threadIdx.x >> 7);
    int c = threadIdx.x & 127;
    if (n >= N) return;
    float dn = dinv[n];
    float acc = H[(size_t)n * D + c] * dn * dn;  // self-loop term
    int beg = offsets[n], end = offsets[n + 1];
    for (int i = beg; i < end; ++i) {
        int s = csr_src[i];
        float cf = csr_coef[i];
        acc = fmaf(H[(size_t)s * D + c], cf, acc);
    }
    Out[(size_t)n * D + c] = fmaxf(acc + bias[c], 0.0f);
}

// ---------------- pooling: segment_sum over sorted batch ----------------
__global__ __launch_bounds__(128) void k_pool(const float* __restrict__ H,
                                              const int* __restrict__ batch,
                                              float* __restrict__ pooled, int N) {
    int c = threadIdx.x;
    int start = blockIdx.x * 512;
    if (start >= N) return;
    int end = min(start + 512, N);
    int g = batch[start];
    float acc = 0.f;
    for (int n = start; n < end; ++n) {
        int gn = batch[n];
        if (gn != g) {
            atomicAdd(&pooled[g * D + c], acc);
            acc = 0.f;
            g = gn;
        }
        acc += H[(size_t)n * D + c];
    }
    atomicAdd(&pooled[g * D + c], acc);
}

// ---------------- final linear: out[512,2] = pooled @ Wlin + blin ----------------
__global__ __launch_bounds__(64) void k_lin(const float* __restrict__ pooled,
                                            const float* __restrict__ Wlin,
                                            const float* __restrict__ blin,
                                            float* __restrict__ out, int G) {
    int g = blockIdx.x;
    int t = threadIdx.x;
    float p0 = pooled[g * D + t];
    float p1 = pooled[g * D + t + 64];
    float a0 = fmaf(p0, Wlin[t * 2 + 0], p1 * Wlin[(t + 64) * 2 + 0]);
    float a1 = fmaf(p0, Wlin[t * 2 + 1], p1 * Wlin[(t + 64) * 2 + 1]);
    for (int off = 32; off > 0; off >>= 1) {
        a0 += __shfl_down(a0, off);
        a1 += __shfl_down(a1, off);
    }
    if (t == 0) {
        out[g * 2 + 0] = a0 + blin[0];
        out[g * 2 + 1] = a1 + blin[1];
    }
}

extern "C" void kernel_launch(void* const* d_in, const int* in_sizes, int n_in,
                              void* d_out, int out_size, void* d_ws, size_t ws_size,
                              hipStream_t stream) {
    const float* x    = (const float*)d_in[0];
    const int*   edge = (const int*)d_in[1];
    const int*   batch= (const int*)d_in[2];
    const float* W1   = (const float*)d_in[3];
    const float* b1   = (const float*)d_in[4];
    const float* W2   = (const float*)d_in[5];
    const float* b2   = (const float*)d_in[6];
    const float* W3   = (const float*)d_in[7];
    const float* b3   = (const float*)d_in[8];
    const float* Wlin = (const float*)d_in[9];
    const float* blin = (const float*)d_in[10];
    float* out = (float*)d_out;

    int N = in_sizes[2];        // 100000 nodes
    int E = in_sizes[1] / 2;    // 1.6M edges
    int G = out_size / 2;       // 512 graphs
    const int* src = edge;
    const int* dst = edge + E;

    char* ws = (char*)d_ws;
    size_t off = 0;
    auto alloc = [&](size_t bytes) -> void* {
        void* p = ws + off;
        off += (bytes + 511) & ~(size_t)511;
        return p;
    };
    int*   degi     = (int*)  alloc((size_t)N * 4);
    float* dinv     = (float*)alloc((size_t)N * 4);
    int*   offsets  = (int*)  alloc((size_t)(N + 1) * 4);
    int*   cursor   = (int*)  alloc((size_t)N * 4);
    int*   csr_src  = (int*)  alloc((size_t)E * 4);
    float* csr_coef = (float*)alloc((size_t)E * 4);
    float* bufA     = (float*)alloc((size_t)N * D * 4);
    float* bufB     = (float*)alloc((size_t)N * D * 4);
    float* pooled   = (float*)alloc((size_t)G * D * 4);
    (void)ws_size; (void)n_in;

    hipMemsetAsync(degi, 0, (size_t)N * 4, stream);
    hipMemsetAsync(pooled, 0, (size_t)G * D * 4, stream);

    k_degree<<<(E + 255) / 256, 256, 0, stream>>>(dst, E, degi);
    k_dinv<<<(N + 255) / 256, 256, 0, stream>>>(degi, dinv, N);
    k_scan<<<1, 1024, 0, stream>>>(degi, offsets, cursor, N);
    k_fill<<<(E + 255) / 256, 256, 0, stream>>>(src, dst, E, dinv, cursor, csr_src, csr_coef);

    int gb = (N + 63) / 64;
    int ab = (N + 1) / 2;
    k_gemm<<<gb, 256, 0, stream>>>(x,    W1, bufA, N);
    k_agg <<<ab, 256, 0, stream>>>(bufA, offsets, csr_src, csr_coef, dinv, b1, bufB, N);
    k_gemm<<<gb, 256, 0, stream>>>(bufB, W2, bufA, N);
    k_agg <<<ab, 256, 0, stream>>>(bufA, offsets, csr_src, csr_coef, dinv, b2, bufB, N);
    k_gemm<<<gb, 256, 0, stream>>>(bufB, W3, bufA, N);
    k_agg <<<ab, 256, 0, stream>>>(bufA, offsets, csr_src, csr_coef, dinv, b3, bufB, N);

    k_pool<<<(N + 511) / 512, 128, 0, stream>>>(bufB, batch, pooled, N);
    k_lin <<<G, 64, 0, stream>>>(pooled, Wlin, blin, out, G);
}

// Round 7
// 1136.513 us; speedup vs baseline: 1.4711x; 1.4711x over previous
//
#include <hip/hip_runtime.h>
#include <hip/hip_bf16.h>

#define D 128

typedef unsigned int uint32;
typedef unsigned short ushort16;

__device__ inline float bf2f(uint32 u16) {
    uint32 v = u16 << 16;
    float f;
    __builtin_memcpy(&f, &v, 4);
    return f;
}
__device__ inline ushort16 f2bf(float f) {
    uint32 u;
    __builtin_memcpy(&u, &f, 4);
    u = (u + 0x7FFFu + ((u >> 16) & 1u)) >> 16;   // round-to-nearest-even
    return (ushort16)u;
}

// ---------------- degree histogram ----------------
__global__ void k_degree(const int* __restrict__ dst, int E, int* __restrict__ degi) {
    int i = blockIdx.x * blockDim.x + threadIdx.x;
    if (i < E) atomicAdd(&degi[dst[i]], 1);
}

__global__ void k_dinv(const int* __restrict__ degi, float* __restrict__ dinv, int N) {
    int i = blockIdx.x * blockDim.x + threadIdx.x;
    if (i < N) dinv[i] = rsqrtf((float)degi[i] + 1.0f);
}

// ---------------- single-block exclusive scan over degrees ----------------
__global__ __launch_bounds__(1024) void k_scan(const int* __restrict__ degi,
                                               int* __restrict__ offsets,
                                               int* __restrict__ cursor, int N) {
    __shared__ int sums[1024];
    int t = threadIdx.x;
    int chunk = (N + 1023) >> 10;
    int beg = t * chunk;
    int end = min(beg + chunk, N);
    int s = 0;
    for (int i = beg; i < end; ++i) s += degi[i];
    sums[t] = s;
    __syncthreads();
    for (int off = 1; off < 1024; off <<= 1) {
        int v = 0;
        if (t >= off) v = sums[t - off];
        __syncthreads();
        sums[t] += v;
        __syncthreads();
    }
    int base = sums[t] - s;
    int run = base;
    for (int i = beg; i < end; ++i) {
        offsets[i] = run;
        cursor[i] = run;
        run += degi[i];
    }
    if (end == N) offsets[N] = run;
}

// ---------------- CSR fill ----------------
__global__ void k_fill(const int* __restrict__ src, const int* __restrict__ dst, int E,
                       const float* __restrict__ dinv, int* __restrict__ cursor,
                       int* __restrict__ csr_src, float* __restrict__ csr_coef) {
    int i = blockIdx.x * blockDim.x + threadIdx.x;
    if (i < E) {
        int s = src[i], d = dst[i];
        int pos = atomicAdd(&cursor[d], 1);
        csr_src[pos] = s;
        csr_coef[pos] = dinv[s] * dinv[d];
    }
}

// ---------------- GEMM (f32 input): H_bf16[N,128] = X[N,128] @ W[128,128] ----------------
__global__ __launch_bounds__(256) void k_gemm_f32in(const float* __restrict__ X,
                                                    const float* __restrict__ W,
                                                    ushort16* __restrict__ H, int N) {
    __shared__ float4 xs[64 * 32];
    int tid = threadIdx.x;
    int base = blockIdx.x * 64;
    const float4* X4 = (const float4*)X;
#pragma unroll
    for (int i = 0; i < 8; ++i) {
        int f4 = tid + i * 256;
        int row = base + (f4 >> 5);
        float4 v = make_float4(0.f, 0.f, 0.f, 0.f);
        if (row < N) v = X4[(size_t)base * 32 + f4];
        xs[f4] = v;
    }
    __syncthreads();

    int c4 = tid & 31;
    int r0 = (tid >> 5) * 8;
    float4 acc[8];
#pragma unroll
    for (int i = 0; i < 8; ++i) acc[i] = make_float4(0.f, 0.f, 0.f, 0.f);

    const float4* W4 = (const float4*)W;
#pragma unroll 2
    for (int k4 = 0; k4 < 32; ++k4) {
        float4 w0 = W4[(k4 * 4 + 0) * 32 + c4];
        float4 w1 = W4[(k4 * 4 + 1) * 32 + c4];
        float4 w2 = W4[(k4 * 4 + 2) * 32 + c4];
        float4 w3 = W4[(k4 * 4 + 3) * 32 + c4];
#pragma unroll
        for (int i = 0; i < 8; ++i) {
            float4 xv = xs[(r0 + i) * 32 + k4];
            acc[i].x = fmaf(xv.x, w0.x, acc[i].x);
            acc[i].y = fmaf(xv.x, w0.y, acc[i].y);
            acc[i].z = fmaf(xv.x, w0.z, acc[i].z);
            acc[i].w = fmaf(xv.x, w0.w, acc[i].w);
            acc[i].x = fmaf(xv.y, w1.x, acc[i].x);
            acc[i].y = fmaf(xv.y, w1.y, acc[i].y);
            acc[i].z = fmaf(xv.y, w1.z, acc[i].z);
            acc[i].w = fmaf(xv.y, w1.w, acc[i].w);
            acc[i].x = fmaf(xv.z, w2.x, acc[i].x);
            acc[i].y = fmaf(xv.z, w2.y, acc[i].y);
            acc[i].z = fmaf(xv.z, w2.z, acc[i].z);
            acc[i].w = fmaf(xv.z, w2.w, acc[i].w);
            acc[i].x = fmaf(xv.w, w3.x, acc[i].x);
            acc[i].y = fmaf(xv.w, w3.y, acc[i].y);
            acc[i].z = fmaf(xv.w, w3.z, acc[i].z);
            acc[i].w = fmaf(xv.w, w3.w, acc[i].w);
        }
    }
#pragma unroll
    for (int i = 0; i < 8; ++i) {
        int row = base + r0 + i;
        if (row < N) {
            ushort4 o;
            o.x = f2bf(acc[i].x); o.y = f2bf(acc[i].y);
            o.z = f2bf(acc[i].z); o.w = f2bf(acc[i].w);
            *(ushort4*)&H[(size_t)row * D + c4 * 4] = o;
        }
    }
}

// ---------------- GEMM (bf16 input): H_bf16 = A_bf16 @ W ----------------
__global__ __launch_bounds__(256) void k_gemm_bf16in(const ushort16* __restrict__ A,
                                                     const float* __restrict__ W,
                                                     ushort16* __restrict__ H, int N) {
    __shared__ float4 xs[64 * 32];
    int tid = threadIdx.x;
    int base = blockIdx.x * 64;
    const uint4* A4 = (const uint4*)A;  // 16 uint4 per 128-bf16 row
#pragma unroll
    for (int i = 0; i < 4; ++i) {
        int u = tid + i * 256;          // [0,1024): row = u>>4, seg = u&15
        int row = base + (u >> 4);
        uint4 v = make_uint4(0, 0, 0, 0);
        if (row < N) v = A4[(size_t)base * 16 + u];
        float4 lo = make_float4(bf2f(v.x & 0xffff), bf2f(v.x >> 16),
                                bf2f(v.y & 0xffff), bf2f(v.y >> 16));
        float4 hi = make_float4(bf2f(v.z & 0xffff), bf2f(v.z >> 16),
                                bf2f(v.w & 0xffff), bf2f(v.w >> 16));
        int r = u >> 4, sgm = u & 15;
        xs[r * 32 + sgm * 2 + 0] = lo;
        xs[r * 32 + sgm * 2 + 1] = hi;
    }
    __syncthreads();

    int c4 = tid & 31;
    int r0 = (tid >> 5) * 8;
    float4 acc[8];
#pragma unroll
    for (int i = 0; i < 8; ++i) acc[i] = make_float4(0.f, 0.f, 0.f, 0.f);

    const float4* W4 = (const float4*)W;
#pragma unroll 2
    for (int k4 = 0; k4 < 32; ++k4) {
        float4 w0 = W4[(k4 * 4 + 0) * 32 + c4];
        float4 w1 = W4[(k4 * 4 + 1) * 32 + c4];
        float4 w2 = W4[(k4 * 4 + 2) * 32 + c4];
        float4 w3 = W4[(k4 * 4 + 3) * 32 + c4];
#pragma unroll
        for (int i = 0; i < 8; ++i) {
            float4 xv = xs[(r0 + i) * 32 + k4];
            acc[i].x = fmaf(xv.x, w0.x, acc[i].x);
            acc[i].y = fmaf(xv.x, w0.y, acc[i].y);
            acc[i].z = fmaf(xv.x, w0.z, acc[i].z);
            acc[i].w = fmaf(xv.x, w0.w, acc[i].w);
            acc[i].x = fmaf(xv.y, w1.x, acc[i].x);
            acc[i].y = fmaf(xv.y, w1.y, acc[i].y);
            acc[i].z = fmaf(xv.y, w1.z, acc[i].z);
            acc[i].w = fmaf(xv.y, w1.w, acc[i].w);
            acc[i].x = fmaf(xv.z, w2.x, acc[i].x);
            acc[i].y = fmaf(xv.z, w2.y, acc[i].y);
            acc[i].z = fmaf(xv.z, w2.z, acc[i].z);
            acc[i].w = fmaf(xv.z, w2.w, acc[i].w);
            acc[i].x = fmaf(xv.w, w3.x, acc[i].x);
            acc[i].y = fmaf(xv.w, w3.y, acc[i].y);
            acc[i].z = fmaf(xv.w, w3.z, acc[i].z);
            acc[i].w = fmaf(xv.w, w3.w, acc[i].w);
        }
    }
#pragma unroll
    for (int i = 0; i < 8; ++i) {
        int row = base + r0 + i;
        if (row < N) {
            ushort4 o;
            o.x = f2bf(acc[i].x); o.y = f2bf(acc[i].y);
            o.z = f2bf(acc[i].z); o.w = f2bf(acc[i].w);
            *(ushort4*)&H[(size_t)row * D + c4 * 4] = o;
        }
    }
}

// ---------------- aggregation (bf16 H): Out = relu(norm-agg(H) + b), bf16 out ----------
// 64 lanes per node, 2 features/lane (uint=2xbf16), edge loop unrolled x2
__global__ __launch_bounds__(256) void k_aggb(const ushort16* __restrict__ H,
                                              const int* __restrict__ offsets,
                                              const int* __restrict__ csr_src,
                                              const float* __restrict__ csr_coef,
                                              const float* __restrict__ dinv,
                                              const float* __restrict__ bias,
                                              ushort16* __restrict__ Out, int N) {
    int n = blockIdx.x * 4 + (threadIdx.x >> 6);
    int c2 = threadIdx.x & 63;
    if (n >= N) return;
    const uint32* H2 = (const uint32*)H;
    float dn = dinv[n];
    float dn2 = dn * dn;
    uint32 self = H2[(size_t)n * 64 + c2];
    float a0 = bf2f(self & 0xffff) * dn2;
    float a1 = bf2f(self >> 16) * dn2;
    int beg = offsets[n], end = offsets[n + 1];
    int i = beg;
    for (; i + 2 <= end; i += 2) {
        int s0 = csr_src[i], s1 = csr_src[i + 1];
        float c0 = csr_coef[i], c1 = csr_coef[i + 1];
        uint32 v0 = H2[(size_t)s0 * 64 + c2];
        uint32 v1 = H2[(size_t)s1 * 64 + c2];
        a0 = fmaf(bf2f(v0 & 0xffff), c0, a0);
        a1 = fmaf(bf2f(v0 >> 16), c0, a1);
        a0 = fmaf(bf2f(v1 & 0xffff), c1, a0);
        a1 = fmaf(bf2f(v1 >> 16), c1, a1);
    }
    if (i < end) {
        int s0 = csr_src[i];
        float c0 = csr_coef[i];
        uint32 v0 = H2[(size_t)s0 * 64 + c2];
        a0 = fmaf(bf2f(v0 & 0xffff), c0, a0);
        a1 = fmaf(bf2f(v0 >> 16), c0, a1);
    }
    float2 b2 = ((const float2*)bias)[c2];
    a0 = fmaxf(a0 + b2.x, 0.f);
    a1 = fmaxf(a1 + b2.y, 0.f);
    ((uint32*)Out)[(size_t)n * 64 + c2] = (uint32)f2bf(a0) | ((uint32)f2bf(a1) << 16);
}

// ---------------- pooling: segment_sum over sorted batch (bf16 in, f32 atomics) ----------
__global__ __launch_bounds__(128) void k_poolb(const ushort16* __restrict__ H,
                                               const int* __restrict__ batch,
                                               float* __restrict__ pooled, int N) {
    int c = threadIdx.x;
    int start = blockIdx.x * 512;
    if (start >= N) return;
    int end = min(start + 512, N);
    int g = batch[start];
    float acc = 0.f;
    for (int n = start; n < end; ++n) {
        int gn = batch[n];
        if (gn != g) {
            atomicAdd(&pooled[g * D + c], acc);
            acc = 0.f;
            g = gn;
        }
        acc += bf2f(H[(size_t)n * D + c]);
    }
    atomicAdd(&pooled[g * D + c], acc);
}

// ---------------- final linear ----------------
__global__ __launch_bounds__(64) void k_lin(const float* __restrict__ pooled,
                                            const float* __restrict__ Wlin,
                                            const float* __restrict__ blin,
                                            float* __restrict__ out, int G) {
    int g = blockIdx.x;
    int t = threadIdx.x;
    float p0 = pooled[g * D + t];
    float p1 = pooled[g * D + t + 64];
    float a0 = fmaf(p0, Wlin[t * 2 + 0], p1 * Wlin[(t + 64) * 2 + 0]);
    float a1 = fmaf(p0, Wlin[t * 2 + 1], p1 * Wlin[(t + 64) * 2 + 1]);
    for (int off = 32; off > 0; off >>= 1) {
        a0 += __shfl_down(a0, off);
        a1 += __shfl_down(a1, off);
    }
    if (t == 0) {
        out[g * 2 + 0] = a0 + blin[0];
        out[g * 2 + 1] = a1 + blin[1];
    }
}

extern "C" void kernel_launch(void* const* d_in, const int* in_sizes, int n_in,
                              void* d_out, int out_size, void* d_ws, size_t ws_size,
                              hipStream_t stream) {
    const float* x    = (const float*)d_in[0];
    const int*   edge = (const int*)d_in[1];
    const int*   batch= (const int*)d_in[2];
    const float* W1   = (const float*)d_in[3];
    const float* b1   = (const float*)d_in[4];
    const float* W2   = (const float*)d_in[5];
    const float* b2   = (const float*)d_in[6];
    const float* W3   = (const float*)d_in[7];
    const float* b3   = (const float*)d_in[8];
    const float* Wlin = (const float*)d_in[9];
    const float* blin = (const float*)d_in[10];
    float* out = (float*)d_out;

    int N = in_sizes[2];
    int E = in_sizes[1] / 2;
    int G = out_size / 2;
    const int* src = edge;
    const int* dst = edge + E;

    char* ws = (char*)d_ws;
    size_t off = 0;
    auto alloc = [&](size_t bytes) -> void* {
        void* p = ws + off;
        off += (bytes + 511) & ~(size_t)511;
        return p;
    };
    int*      degi     = (int*)     alloc((size_t)N * 4);
    float*    dinv     = (float*)   alloc((size_t)N * 4);
    int*      offsets  = (int*)     alloc((size_t)(N + 1) * 4);
    int*      cursor   = (int*)     alloc((size_t)N * 4);
    int*      csr_src  = (int*)     alloc((size_t)E * 4);
    float*    csr_coef = (float*)   alloc((size_t)E * 4);
    ushort16* bufA     = (ushort16*)alloc((size_t)N * D * 2);
    ushort16* bufB     = (ushort16*)alloc((size_t)N * D * 2);
    float*    pooled   = (float*)   alloc((size_t)G * D * 4);
    (void)ws_size; (void)n_in;

    hipMemsetAsync(degi, 0, (size_t)N * 4, stream);
    hipMemsetAsync(pooled, 0, (size_t)G * D * 4, stream);

    k_degree<<<(E + 255) / 256, 256, 0, stream>>>(dst, E, degi);
    k_dinv<<<(N + 255) / 256, 256, 0, stream>>>(degi, dinv, N);
    k_scan<<<1, 1024, 0, stream>>>(degi, offsets, cursor, N);
    k_fill<<<(E + 255) / 256, 256, 0, stream>>>(src, dst, E, dinv, cursor, csr_src, csr_coef);

    int gb = (N + 63) / 64;
    int ab = (N + 3) / 4;
    k_gemm_f32in <<<gb, 256, 0, stream>>>(x,    W1, bufA, N);
    k_aggb       <<<ab, 256, 0, stream>>>(bufA, offsets, csr_src, csr_coef, dinv, b1, bufB, N);
    k_gemm_bf16in<<<gb, 256, 0, stream>>>(bufB, W2, bufA, N);
    k_aggb       <<<ab, 256, 0, stream>>>(bufA, offsets, csr_src, csr_coef, dinv, b2, bufB, N);
    k_gemm_bf16in<<<gb, 256, 0, stream>>>(bufB, W3, bufA, N);
    k_aggb       <<<ab, 256, 0, stream>>>(bufA, offsets, csr_src, csr_coef, dinv, b3, bufB, N);

    k_poolb<<<(N + 511) / 512, 128, 0, stream>>>(bufB, batch, pooled, N);
    k_lin  <<<G, 64, 0, stream>>>(pooled, Wlin, blin, out, G);
}

// Round 11
// 911.651 us; speedup vs baseline: 1.8340x; 1.2467x over previous
//
#include <hip/hip_runtime.h>
#include <hip/hip_bf16.h>

#define D 128
#define SCHUNK 1024  // elements per scan block

typedef unsigned int uint32;
typedef unsigned short ushort16;

__device__ inline float bf2f(uint32 u16) {
    uint32 v = u16 << 16;
    float f;
    __builtin_memcpy(&f, &v, 4);
    return f;
}
__device__ inline ushort16 f2bf(float f) {
    uint32 u;
    __builtin_memcpy(&u, &f, 4);
    u = (u + 0x7FFFu + ((u >> 16) & 1u)) >> 16;   // round-to-nearest-even
    return (ushort16)u;
}

// ---------------- degree histogram ----------------
__global__ void k_degree(const int* __restrict__ dst, int E, int* __restrict__ degi) {
    int i = blockIdx.x * blockDim.x + threadIdx.x;
    if (i < E) atomicAdd(&degi[dst[i]], 1);
}

__global__ void k_dinv(const int* __restrict__ degi, float* __restrict__ dinv, int N) {
    int i = blockIdx.x * blockDim.x + threadIdx.x;
    if (i < N) dinv[i] = rsqrtf((float)degi[i] + 1.0f);
}

// ---------------- multi-block exclusive scan: phase A (block partial sums) ----------------
__global__ __launch_bounds__(256) void k_scanA(const int* __restrict__ degi,
                                               int* __restrict__ blockSums, int N) {
    __shared__ int red[256];
    int b = blockIdx.x, t = threadIdx.x;
    int base = b * SCHUNK;
    const int4* d4 = (const int4*)(degi + base);
    int4 v = make_int4(0, 0, 0, 0);
    int idx = base + t * 4;
    if (idx + 3 < N) v = d4[t];
    else {
        if (idx + 0 < N) v.x = degi[idx + 0];
        if (idx + 1 < N) v.y = degi[idx + 1];
        if (idx + 2 < N) v.z = degi[idx + 2];
        if (idx + 3 < N) v.w = degi[idx + 3];
    }
    red[t] = v.x + v.y + v.z + v.w;
    __syncthreads();
    for (int off = 128; off > 0; off >>= 1) {
        if (t < off) red[t] += red[t + off];
        __syncthreads();
    }
    if (t == 0) blockSums[b] = red[0];
}

// ---------------- phase B: single block exclusive scan of B block sums (B<=1024) --------
__global__ __launch_bounds__(1024) void k_scanB(int* __restrict__ blockSums, int B) {
    __shared__ int sums[1024];
    int t = threadIdx.x;
    int v = (t < B) ? blockSums[t] : 0;
    sums[t] = v;
    __syncthreads();
    for (int off = 1; off < 1024; off <<= 1) {
        int u = (t >= off) ? sums[t - off] : 0;
        __syncthreads();
        sums[t] += u;
        __syncthreads();
    }
    if (t < B) blockSums[t] = sums[t] - v;  // exclusive block base
}

// ---------------- phase C: per-block scan + write offsets/cursor --------------------------
__global__ __launch_bounds__(256) void k_scanC(const int* __restrict__ degi,
                                               const int* __restrict__ blockSums,
                                               int* __restrict__ offsets,
                                               int* __restrict__ cursor, int N, int E) {
    __shared__ int sums[256];
    int b = blockIdx.x, t = threadIdx.x;
    int base = b * SCHUNK;
    const int4* d4 = (const int4*)(degi + base);
    int4 v = make_int4(0, 0, 0, 0);
    int idx = base + t * 4;
    if (idx + 3 < N) v = d4[t];
    else {
        if (idx + 0 < N) v.x = degi[idx + 0];
        if (idx + 1 < N) v.y = degi[idx + 1];
        if (idx + 2 < N) v.z = degi[idx + 2];
        if (idx + 3 < N) v.w = degi[idx + 3];
    }
    int loc = v.x + v.y + v.z + v.w;
    sums[t] = loc;
    __syncthreads();
    for (int off = 1; off < 256; off <<= 1) {
        int u = (t >= off) ? sums[t - off] : 0;
        __syncthreads();
        sums[t] += u;
        __syncthreads();
    }
    int run = sums[t] - loc + blockSums[b];
    int vals[4] = {v.x, v.y, v.z, v.w};
#pragma unroll
    for (int j = 0; j < 4; ++j) {
        int i2 = idx + j;
        if (i2 < N) { offsets[i2] = run; cursor[i2] = run; }
        run += vals[j];
    }
    if (b == 0 && t == 0) offsets[N] = E;  // total degree == E by construction
}

// ---------------- CSR fill ----------------
__global__ void k_fill(const int* __restrict__ src, const int* __restrict__ dst, int E,
                       const float* __restrict__ dinv, int* __restrict__ cursor,
                       int* __restrict__ csr_src, float* __restrict__ csr_coef) {
    int i = blockIdx.x * blockDim.x + threadIdx.x;
    if (i < E) {
        int s = src[i], d = dst[i];
        int pos = atomicAdd(&cursor[d], 1);
        csr_src[pos] = s;
        csr_coef[pos] = dinv[s] * dinv[d];
    }
}

// ---------------- GEMM (f32 input): H_bf16[N,128] = X[N,128] @ W[128,128] ----------------
__global__ __launch_bounds__(256) void k_gemm_f32in(const float* __restrict__ X,
                                                    const float* __restrict__ W,
                                                    ushort16* __restrict__ H, int N) {
    __shared__ float4 xs[64 * 32];
    int tid = threadIdx.x;
    int base = blockIdx.x * 64;
    const float4* X4 = (const float4*)X;
#pragma unroll
    for (int i = 0; i < 8; ++i) {
        int f4 = tid + i * 256;
        int row = base + (f4 >> 5);
        float4 v = make_float4(0.f, 0.f, 0.f, 0.f);
        if (row < N) v = X4[(size_t)base * 32 + f4];
        xs[f4] = v;
    }
    __syncthreads();

    int c4 = tid & 31;
    int r0 = (tid >> 5) * 8;
    float4 acc[8];
#pragma unroll
    for (int i = 0; i < 8; ++i) acc[i] = make_float4(0.f, 0.f, 0.f, 0.f);

    const float4* W4 = (const float4*)W;
#pragma unroll 2
    for (int k4 = 0; k4 < 32; ++k4) {
        float4 w0 = W4[(k4 * 4 + 0) * 32 + c4];
        float4 w1 = W4[(k4 * 4 + 1) * 32 + c4];
        float4 w2 = W4[(k4 * 4 + 2) * 32 + c4];
        float4 w3 = W4[(k4 * 4 + 3) * 32 + c4];
#pragma unroll
        for (int i = 0; i < 8; ++i) {
            float4 xv = xs[(r0 + i) * 32 + k4];
            acc[i].x = fmaf(xv.x, w0.x, acc[i].x);
            acc[i].y = fmaf(xv.x, w0.y, acc[i].y);
            acc[i].z = fmaf(xv.x, w0.z, acc[i].z);
            acc[i].w = fmaf(xv.x, w0.w, acc[i].w);
            acc[i].x = fmaf(xv.y, w1.x, acc[i].x);
            acc[i].y = fmaf(xv.y, w1.y, acc[i].y);
            acc[i].z = fmaf(xv.y, w1.z, acc[i].z);
            acc[i].w = fmaf(xv.y, w1.w, acc[i].w);
            acc[i].x = fmaf(xv.z, w2.x, acc[i].x);
            acc[i].y = fmaf(xv.z, w2.y, acc[i].y);
            acc[i].z = fmaf(xv.z, w2.z, acc[i].z);
            acc[i].w = fmaf(xv.z, w2.w, acc[i].w);
            acc[i].x = fmaf(xv.w, w3.x, acc[i].x);
            acc[i].y = fmaf(xv.w, w3.y, acc[i].y);
            acc[i].z = fmaf(xv.w, w3.z, acc[i].z);
            acc[i].w = fmaf(xv.w, w3.w, acc[i].w);
        }
    }
#pragma unroll
    for (int i = 0; i < 8; ++i) {
        int row = base + r0 + i;
        if (row < N) {
            ushort4 o;
            o.x = f2bf(acc[i].x); o.y = f2bf(acc[i].y);
            o.z = f2bf(acc[i].z); o.w = f2bf(acc[i].w);
            *(ushort4*)&H[(size_t)row * D + c4 * 4] = o;
        }
    }
}

// ---------------- GEMM (bf16 input): H_bf16 = A_bf16 @ W ----------------
__global__ __launch_bounds__(256) void k_gemm_bf16in(const ushort16* __restrict__ A,
                                                     const float* __restrict__ W,
                                                     ushort16* __restrict__ H, int N) {
    __shared__ float4 xs[64 * 32];
    int tid = threadIdx.x;
    int base = blockIdx.x * 64;
    const uint4* A4 = (const uint4*)A;  // 16 uint4 per 128-bf16 row
#pragma unroll
    for (int i = 0; i < 4; ++i) {
        int u = tid + i * 256;          // [0,1024): row = u>>4, seg = u&15
        int row = base + (u >> 4);
        uint4 v = make_uint4(0, 0, 0, 0);
        if (row < N) v = A4[(size_t)base * 16 + u];
        float4 lo = make_float4(bf2f(v.x & 0xffff), bf2f(v.x >> 16),
                                bf2f(v.y & 0xffff), bf2f(v.y >> 16));
        float4 hi = make_float4(bf2f(v.z & 0xffff), bf2f(v.z >> 16),
                                bf2f(v.w & 0xffff), bf2f(v.w >> 16));
        int r = u >> 4, sgm = u & 15;
        xs[r * 32 + sgm * 2 + 0] = lo;
        xs[r * 32 + sgm * 2 + 1] = hi;
    }
    __syncthreads();

    int c4 = tid & 31;
    int r0 = (tid >> 5) * 8;
    float4 acc[8];
#pragma unroll
    for (int i = 0; i < 8; ++i) acc[i] = make_float4(0.f, 0.f, 0.f, 0.f);

    const float4* W4 = (const float4*)W;
#pragma unroll 2
    for (int k4 = 0; k4 < 32; ++k4) {
        float4 w0 = W4[(k4 * 4 + 0) * 32 + c4];
        float4 w1 = W4[(k4 * 4 + 1) * 32 + c4];
        float4 w2 = W4[(k4 * 4 + 2) * 32 + c4];
        float4 w3 = W4[(k4 * 4 + 3) * 32 + c4];
#pragma unroll
        for (int i = 0; i < 8; ++i) {
            float4 xv = xs[(r0 + i) * 32 + k4];
            acc[i].x = fmaf(xv.x, w0.x, acc[i].x);
            acc[i].y = fmaf(xv.x, w0.y, acc[i].y);
            acc[i].z = fmaf(xv.x, w0.z, acc[i].z);
            acc[i].w = fmaf(xv.x, w0.w, acc[i].w);
            acc[i].x = fmaf(xv.y, w1.x, acc[i].x);
            acc[i].y = fmaf(xv.y, w1.y, acc[i].y);
            acc[i].z = fmaf(xv.y, w1.z, acc[i].z);
            acc[i].w = fmaf(xv.y, w1.w, acc[i].w);
            acc[i].x = fmaf(xv.z, w2.x, acc[i].x);
            acc[i].y = fmaf(xv.z, w2.y, acc[i].y);
            acc[i].z = fmaf(xv.z, w2.z, acc[i].z);
            acc[i].w = fmaf(xv.z, w2.w, acc[i].w);
            acc[i].x = fmaf(xv.w, w3.x, acc[i].x);
            acc[i].y = fmaf(xv.w, w3.y, acc[i].y);
            acc[i].z = fmaf(xv.w, w3.z, acc[i].z);
            acc[i].w = fmaf(xv.w, w3.w, acc[i].w);
        }
    }
#pragma unroll
    for (int i = 0; i < 8; ++i) {
        int row = base + r0 + i;
        if (row < N) {
            ushort4 o;
            o.x = f2bf(acc[i].x); o.y = f2bf(acc[i].y);
            o.z = f2bf(acc[i].z); o.w = f2bf(acc[i].w);
            *(ushort4*)&H[(size_t)row * D + c4 * 4] = o;
        }
    }
}

// ---------------- aggregation (bf16 H): Out = relu(norm-agg(H) + b), bf16 out ----------
__global__ __launch_bounds__(256) void k_aggb(const ushort16* __restrict__ H,
                                              const int* __restrict__ offsets,
                                              const int* __restrict__ csr_src,
                                              const float* __restrict__ csr_coef,
                                              const float* __restrict__ dinv,
                                              const float* __restrict__ bias,
                                              ushort16* __restrict__ Out, int N) {
    int n = blockIdx.x * 4 + (threadIdx.x >> 6);
    int c2 = threadIdx.x & 63;
    if (n >= N) return;
    const uint32* H2 = (const uint32*)H;
    float dn = dinv[n];
    float dn2 = dn * dn;
    uint32 self = H2[(size_t)n * 64 + c2];
    float a0 = bf2f(self & 0xffff) * dn2;
    float a1 = bf2f(self >> 16) * dn2;
    int beg = offsets[n], end = offsets[n + 1];
    int i = beg;
    for (; i + 2 <= end; i += 2) {
        int s0 = csr_src[i], s1 = csr_src[i + 1];
        float c0 = csr_coef[i], c1 = csr_coef[i + 1];
        uint32 v0 = H2[(size_t)s0 * 64 + c2];
        uint32 v1 = H2[(size_t)s1 * 64 + c2];
        a0 = fmaf(bf2f(v0 & 0xffff), c0, a0);
        a1 = fmaf(bf2f(v0 >> 16), c0, a1);
        a0 = fmaf(bf2f(v1 & 0xffff), c1, a0);
        a1 = fmaf(bf2f(v1 >> 16), c1, a1);
    }
    if (i < end) {
        int s0 = csr_src[i];
        float c0 = csr_coef[i];
        uint32 v0 = H2[(size_t)s0 * 64 + c2];
        a0 = fmaf(bf2f(v0 & 0xffff), c0, a0);
        a1 = fmaf(bf2f(v0 >> 16), c0, a1);
    }
    float2 b2 = ((const float2*)bias)[c2];
    a0 = fmaxf(a0 + b2.x, 0.f);
    a1 = fmaxf(a1 + b2.y, 0.f);
    ((uint32*)Out)[(size_t)n * 64 + c2] = (uint32)f2bf(a0) | ((uint32)f2bf(a1) << 16);
}

// ---------------- pooling: segment_sum over sorted batch (bf16 in, f32 atomics) ----------
__global__ __launch_bounds__(128) void k_poolb(const ushort16* __restrict__ H,
                                               const int* __restrict__ batch,
                                               float* __restrict__ pooled, int N) {
    int c = threadIdx.x;
    int start = blockIdx.x * 512;
    if (start >= N) return;
    int end = min(start + 512, N);
    int g = batch[start];
    float acc = 0.f;
    for (int n = start; n < end; ++n) {
        int gn = batch[n];
        if (gn != g) {
            atomicAdd(&pooled[g * D + c], acc);
            acc = 0.f;
            g = gn;
        }
        acc += bf2f(H[(size_t)n * D + c]);
    }
    atomicAdd(&pooled[g * D + c], acc);
}

// ---------------- final linear ----------------
__global__ __launch_bounds__(64) void k_lin(const float* __restrict__ pooled,
                                            const float* __restrict__ Wlin,
                                            const float* __restrict__ blin,
                                            float* __restrict__ out, int G) {
    int g = blockIdx.x;
    int t = threadIdx.x;
    float p0 = pooled[g * D + t];
    float p1 = pooled[g * D + t + 64];
    float a0 = fmaf(p0, Wlin[t * 2 + 0], p1 * Wlin[(t + 64) * 2 + 0]);
    float a1 = fmaf(p0, Wlin[t * 2 + 1], p1 * Wlin[(t + 64) * 2 + 1]);
    for (int off = 32; off > 0; off >>= 1) {
        a0 += __shfl_down(a0, off);
        a1 += __shfl_down(a1, off);
    }
    if (t == 0) {
        out[g * 2 + 0] = a0 + blin[0];
        out[g * 2 + 1] = a1 + blin[1];
    }
}

extern "C" void kernel_launch(void* const* d_in, const int* in_sizes, int n_in,
                              void* d_out, int out_size, void* d_ws, size_t ws_size,
                              hipStream_t stream) {
    const float* x    = (const float*)d_in[0];
    const int*   edge = (const int*)d_in[1];
    const int*   batch= (const int*)d_in[2];
    const float* W1   = (const float*)d_in[3];
    const float* b1   = (const float*)d_in[4];
    const float* W2   = (const float*)d_in[5];
    const float* b2   = (const float*)d_in[6];
    const float* W3   = (const float*)d_in[7];
    const float* b3   = (const float*)d_in[8];
    const float* Wlin = (const float*)d_in[9];
    const float* blin = (const float*)d_in[10];
    float* out = (float*)d_out;

    int N = in_sizes[2];
    int E = in_sizes[1] / 2;
    int G = out_size / 2;
    const int* src = edge;
    const int* dst = edge + E;

    char* ws = (char*)d_ws;
    size_t off = 0;
    auto alloc = [&](size_t bytes) -> void* {
        void* p = ws + off;
        off += (bytes + 511) & ~(size_t)511;
        return p;
    };
    int*      degi     = (int*)     alloc((size_t)N * 4);
    float*    dinv     = (float*)   alloc((size_t)N * 4);
    int*      offsets  = (int*)     alloc((size_t)(N + 1) * 4);
    int*      cursor   = (int*)     alloc((size_t)N * 4);
    int*      csr_src  = (int*)     alloc((size_t)E * 4);
    float*    csr_coef = (float*)   alloc((size_t)E * 4);
    ushort16* bufA     = (ushort16*)alloc((size_t)N * D * 2);
    ushort16* bufB     = (ushort16*)alloc((size_t)N * D * 2);
    float*    pooled   = (float*)   alloc((size_t)G * D * 4);
    int*      blockSums= (int*)     alloc((size_t)1024 * 4);
    (void)ws_size; (void)n_in;

    hipMemsetAsync(degi, 0, (size_t)N * 4, stream);
    hipMemsetAsync(pooled, 0, (size_t)G * D * 4, stream);

    int SB = (N + SCHUNK - 1) / SCHUNK;  // scan blocks (98 for N=100000)
    k_degree<<<(E + 255) / 256, 256, 0, stream>>>(dst, E, degi);
    k_dinv<<<(N + 255) / 256, 256, 0, stream>>>(degi, dinv, N);
    k_scanA<<<SB, 256, 0, stream>>>(degi, blockSums, N);
    k_scanB<<<1, 1024, 0, stream>>>(blockSums, SB);
    k_scanC<<<SB, 256, 0, stream>>>(degi, blockSums, offsets, cursor, N, E);
    k_fill<<<(E + 255) / 256, 256, 0, stream>>>(src, dst, E, dinv, cursor, csr_src, csr_coef);

    int gb = (N + 63) / 64;
    int ab = (N + 3) / 4;
    k_gemm_f32in <<<gb, 256, 0, stream>>>(x,    W1, bufA, N);
    k_aggb       <<<ab, 256, 0, stream>>>(bufA, offsets, csr_src, csr_coef, dinv, b1, bufB, N);
    k_gemm_bf16in<<<gb, 256, 0, stream>>>(bufB, W2, bufA, N);
    k_aggb       <<<ab, 256, 0, stream>>>(bufA, offsets, csr_src, csr_coef, dinv, b2, bufB, N);
    k_gemm_bf16in<<<gb, 256, 0, stream>>>(bufB, W3, bufA, N);
    k_aggb       <<<ab, 256, 0, stream>>>(bufA, offsets, csr_src, csr_coef, dinv, b3, bufB, N);

    k_poolb<<<(N + 511) / 512, 128, 0, stream>>>(bufB, batch, pooled, N);
    k_lin  <<<G, 64, 0, stream>>>(pooled, Wlin, blin, out, G);
}

// Round 12
// 714.149 us; speedup vs baseline: 2.3412x; 1.2766x over previous
//
#include <hip/hip_runtime.h>
#include <hip/hip_bf16.h>

#define D 128
#define SCHUNK 1024  // elements per scan block

typedef unsigned int uint32;
typedef unsigned short ushort16;

__device__ inline float bf2f(uint32 u16) {
    uint32 v = u16 << 16;
    float f;
    __builtin_memcpy(&f, &v, 4);
    return f;
}
__device__ inline ushort16 f2bf(float f) {
    uint32 u;
    __builtin_memcpy(&u, &f, 4);
    u = (u + 0x7FFFu + ((u >> 16) & 1u)) >> 16;   // round-to-nearest-even
    return (ushort16)u;
}

// ---------------- degree histogram ----------------
__global__ void k_degree(const int* __restrict__ dst, int E, int* __restrict__ degi) {
    int i = blockIdx.x * blockDim.x + threadIdx.x;
    if (i < E) atomicAdd(&degi[dst[i]], 1);
}

__global__ void k_dinv(const int* __restrict__ degi, float* __restrict__ dinv, int N) {
    int i = blockIdx.x * blockDim.x + threadIdx.x;
    if (i < N) dinv[i] = rsqrtf((float)degi[i] + 1.0f);
}

// ---------------- multi-block exclusive scan: phase A (block partial sums) ----------------
__global__ __launch_bounds__(256) void k_scanA(const int* __restrict__ degi,
                                               int* __restrict__ blockSums, int N) {
    __shared__ int red[256];
    int b = blockIdx.x, t = threadIdx.x;
    int base = b * SCHUNK;
    const int4* d4 = (const int4*)(degi + base);
    int4 v = make_int4(0, 0, 0, 0);
    int idx = base + t * 4;
    if (idx + 3 < N) v = d4[t];
    else {
        if (idx + 0 < N) v.x = degi[idx + 0];
        if (idx + 1 < N) v.y = degi[idx + 1];
        if (idx + 2 < N) v.z = degi[idx + 2];
        if (idx + 3 < N) v.w = degi[idx + 3];
    }
    red[t] = v.x + v.y + v.z + v.w;
    __syncthreads();
    for (int off = 128; off > 0; off >>= 1) {
        if (t < off) red[t] += red[t + off];
        __syncthreads();
    }
    if (t == 0) blockSums[b] = red[0];
}

// ---------------- phase B: single block exclusive scan of B block sums (B<=1024) --------
__global__ __launch_bounds__(1024) void k_scanB(int* __restrict__ blockSums, int B) {
    __shared__ int sums[1024];
    int t = threadIdx.x;
    int v = (t < B) ? blockSums[t] : 0;
    sums[t] = v;
    __syncthreads();
    for (int off = 1; off < 1024; off <<= 1) {
        int u = (t >= off) ? sums[t - off] : 0;
        __syncthreads();
        sums[t] += u;
        __syncthreads();
    }
    if (t < B) blockSums[t] = sums[t] - v;  // exclusive block base
}

// ---------------- phase C: per-block scan + write offsets/cursor --------------------------
__global__ __launch_bounds__(256) void k_scanC(const int* __restrict__ degi,
                                               const int* __restrict__ blockSums,
                                               int* __restrict__ offsets,
                                               int* __restrict__ cursor, int N, int E) {
    __shared__ int sums[256];
    int b = blockIdx.x, t = threadIdx.x;
    int base = b * SCHUNK;
    const int4* d4 = (const int4*)(degi + base);
    int4 v = make_int4(0, 0, 0, 0);
    int idx = base + t * 4;
    if (idx + 3 < N) v = d4[t];
    else {
        if (idx + 0 < N) v.x = degi[idx + 0];
        if (idx + 1 < N) v.y = degi[idx + 1];
        if (idx + 2 < N) v.z = degi[idx + 2];
        if (idx + 3 < N) v.w = degi[idx + 3];
    }
    int loc = v.x + v.y + v.z + v.w;
    sums[t] = loc;
    __syncthreads();
    for (int off = 1; off < 256; off <<= 1) {
        int u = (t >= off) ? sums[t - off] : 0;
        __syncthreads();
        sums[t] += u;
        __syncthreads();
    }
    int run = sums[t] - loc + blockSums[b];
    int vals[4] = {v.x, v.y, v.z, v.w};
#pragma unroll
    for (int j = 0; j < 4; ++j) {
        int i2 = idx + j;
        if (i2 < N) { offsets[i2] = run; cursor[i2] = run; }
        run += vals[j];
    }
    if (b == 0 && t == 0) offsets[N] = E;  // total degree == E by construction
}

// ---------------- CSR fill ----------------
__global__ void k_fill(const int* __restrict__ src, const int* __restrict__ dst, int E,
                       const float* __restrict__ dinv, int* __restrict__ cursor,
                       int* __restrict__ csr_src, float* __restrict__ csr_coef) {
    int i = blockIdx.x * blockDim.x + threadIdx.x;
    if (i < E) {
        int s = src[i], d = dst[i];
        int pos = atomicAdd(&cursor[d], 1);
        csr_src[pos] = s;
        csr_coef[pos] = dinv[s] * dinv[d];
    }
}

// ---------------- GEMM (f32 input): H_bf16[N,128] = X[N,128] @ W[128,128] ----------------
__global__ __launch_bounds__(256) void k_gemm_f32in(const float* __restrict__ X,
                                                    const float* __restrict__ W,
                                                    ushort16* __restrict__ H, int N) {
    __shared__ float4 xs[64 * 32];
    int tid = threadIdx.x;
    int base = blockIdx.x * 64;
    const float4* X4 = (const float4*)X;
#pragma unroll
    for (int i = 0; i < 8; ++i) {
        int f4 = tid + i * 256;
        int row = base + (f4 >> 5);
        float4 v = make_float4(0.f, 0.f, 0.f, 0.f);
        if (row < N) v = X4[(size_t)base * 32 + f4];
        xs[f4] = v;
    }
    __syncthreads();

    int c4 = tid & 31;
    int r0 = (tid >> 5) * 8;
    float4 acc[8];
#pragma unroll
    for (int i = 0; i < 8; ++i) acc[i] = make_float4(0.f, 0.f, 0.f, 0.f);

    const float4* W4 = (const float4*)W;
#pragma unroll 2
    for (int k4 = 0; k4 < 32; ++k4) {
        float4 w0 = W4[(k4 * 4 + 0) * 32 + c4];
        float4 w1 = W4[(k4 * 4 + 1) * 32 + c4];
        float4 w2 = W4[(k4 * 4 + 2) * 32 + c4];
        float4 w3 = W4[(k4 * 4 + 3) * 32 + c4];
#pragma unroll
        for (int i = 0; i < 8; ++i) {
            float4 xv = xs[(r0 + i) * 32 + k4];
            acc[i].x = fmaf(xv.x, w0.x, acc[i].x);
            acc[i].y = fmaf(xv.x, w0.y, acc[i].y);
            acc[i].z = fmaf(xv.x, w0.z, acc[i].z);
            acc[i].w = fmaf(xv.x, w0.w, acc[i].w);
            acc[i].x = fmaf(xv.y, w1.x, acc[i].x);
            acc[i].y = fmaf(xv.y, w1.y, acc[i].y);
            acc[i].z = fmaf(xv.y, w1.z, acc[i].z);
            acc[i].w = fmaf(xv.y, w1.w, acc[i].w);
            acc[i].x = fmaf(xv.z, w2.x, acc[i].x);
            acc[i].y = fmaf(xv.z, w2.y, acc[i].y);
            acc[i].z = fmaf(xv.z, w2.z, acc[i].z);
            acc[i].w = fmaf(xv.z, w2.w, acc[i].w);
            acc[i].x = fmaf(xv.w, w3.x, acc[i].x);
            acc[i].y = fmaf(xv.w, w3.y, acc[i].y);
            acc[i].z = fmaf(xv.w, w3.z, acc[i].z);
            acc[i].w = fmaf(xv.w, w3.w, acc[i].w);
        }
    }
#pragma unroll
    for (int i = 0; i < 8; ++i) {
        int row = base + r0 + i;
        if (row < N) {
            ushort4 o;
            o.x = f2bf(acc[i].x); o.y = f2bf(acc[i].y);
            o.z = f2bf(acc[i].z); o.w = f2bf(acc[i].w);
            *(ushort4*)&H[(size_t)row * D + c4 * 4] = o;
        }
    }
}

// ---------------- GEMM (bf16 input): H_bf16 = A_bf16 @ W ----------------
__global__ __launch_bounds__(256) void k_gemm_bf16in(const ushort16* __restrict__ A,
                                                     const float* __restrict__ W,
                                                     ushort16* __restrict__ H, int N) {
    __shared__ float4 xs[64 * 32];
    int tid = threadIdx.x;
    int base = blockIdx.x * 64;
    const uint4* A4 = (const uint4*)A;  // 16 uint4 per 128-bf16 row
#pragma unroll
    for (int i = 0; i < 4; ++i) {
        int u = tid + i * 256;          // [0,1024): row = u>>4, seg = u&15
        int row = base + (u >> 4);
        uint4 v = make_uint4(0, 0, 0, 0);
        if (row < N) v = A4[(size_t)base * 16 + u];
        float4 lo = make_float4(bf2f(v.x & 0xffff), bf2f(v.x >> 16),
                                bf2f(v.y & 0xffff), bf2f(v.y >> 16));
        float4 hi = make_float4(bf2f(v.z & 0xffff), bf2f(v.z >> 16),
                                bf2f(v.w & 0xffff), bf2f(v.w >> 16));
        int r = u >> 4, sgm = u & 15;
        xs[r * 32 + sgm * 2 + 0] = lo;
        xs[r * 32 + sgm * 2 + 1] = hi;
    }
    __syncthreads();

    int c4 = tid & 31;
    int r0 = (tid >> 5) * 8;
    float4 acc[8];
#pragma unroll
    for (int i = 0; i < 8; ++i) acc[i] = make_float4(0.f, 0.f, 0.f, 0.f);

    const float4* W4 = (const float4*)W;
#pragma unroll 2
    for (int k4 = 0; k4 < 32; ++k4) {
        float4 w0 = W4[(k4 * 4 + 0) * 32 + c4];
        float4 w1 = W4[(k4 * 4 + 1) * 32 + c4];
        float4 w2 = W4[(k4 * 4 + 2) * 32 + c4];
        float4 w3 = W4[(k4 * 4 + 3) * 32 + c4];
#pragma unroll
        for (int i = 0; i < 8; ++i) {
            float4 xv = xs[(r0 + i) * 32 + k4];
            acc[i].x = fmaf(xv.x, w0.x, acc[i].x);
            acc[i].y = fmaf(xv.x, w0.y, acc[i].y);
            acc[i].z = fmaf(xv.x, w0.z, acc[i].z);
            acc[i].w = fmaf(xv.x, w0.w, acc[i].w);
            acc[i].x = fmaf(xv.y, w1.x, acc[i].x);
            acc[i].y = fmaf(xv.y, w1.y, acc[i].y);
            acc[i].z = fmaf(xv.y, w1.z, acc[i].z);
            acc[i].w = fmaf(xv.y, w1.w, acc[i].w);
            acc[i].x = fmaf(xv.z, w2.x, acc[i].x);
            acc[i].y = fmaf(xv.z, w2.y, acc[i].y);
            acc[i].z = fmaf(xv.z, w2.z, acc[i].z);
            acc[i].w = fmaf(xv.z, w2.w, acc[i].w);
            acc[i].x = fmaf(xv.w, w3.x, acc[i].x);
            acc[i].y = fmaf(xv.w, w3.y, acc[i].y);
            acc[i].z = fmaf(xv.w, w3.z, acc[i].z);
            acc[i].w = fmaf(xv.w, w3.w, acc[i].w);
        }
    }
#pragma unroll
    for (int i = 0; i < 8; ++i) {
        int row = base + r0 + i;
        if (row < N) {
            ushort4 o;
            o.x = f2bf(acc[i].x); o.y = f2bf(acc[i].y);
            o.z = f2bf(acc[i].z); o.w = f2bf(acc[i].w);
            *(ushort4*)&H[(size_t)row * D + c4 * 4] = o;
        }
    }
}

// ---------------- aggregation (bf16 H): Out = relu(norm-agg(H) + b), bf16 out ----------
// 64 lanes per node, 2 features/lane; edge loop unrolled x4 (4 gathers in flight)
__global__ __launch_bounds__(256) void k_aggb(const ushort16* __restrict__ H,
                                              const int* __restrict__ offsets,
                                              const int* __restrict__ csr_src,
                                              const float* __restrict__ csr_coef,
                                              const float* __restrict__ dinv,
                                              const float* __restrict__ bias,
                                              ushort16* __restrict__ Out, int N) {
    int n = blockIdx.x * 4 + (threadIdx.x >> 6);
    int c2 = threadIdx.x & 63;
    if (n >= N) return;
    const uint32* H2 = (const uint32*)H;
    float dn = dinv[n];
    float dn2 = dn * dn;
    uint32 self = H2[(size_t)n * 64 + c2];
    float a0 = bf2f(self & 0xffff) * dn2;
    float a1 = bf2f(self >> 16) * dn2;
    int beg = offsets[n], end = offsets[n + 1];
    int i = beg;
    for (; i + 4 <= end; i += 4) {
        int s0 = csr_src[i + 0], s1 = csr_src[i + 1];
        int s2 = csr_src[i + 2], s3 = csr_src[i + 3];
        float c0 = csr_coef[i + 0], c1 = csr_coef[i + 1];
        float cc2 = csr_coef[i + 2], c3 = csr_coef[i + 3];
        uint32 v0 = H2[(size_t)s0 * 64 + c2];
        uint32 v1 = H2[(size_t)s1 * 64 + c2];
        uint32 v2 = H2[(size_t)s2 * 64 + c2];
        uint32 v3 = H2[(size_t)s3 * 64 + c2];
        a0 = fmaf(bf2f(v0 & 0xffff), c0, a0);
        a1 = fmaf(bf2f(v0 >> 16), c0, a1);
        a0 = fmaf(bf2f(v1 & 0xffff), c1, a0);
        a1 = fmaf(bf2f(v1 >> 16), c1, a1);
        a0 = fmaf(bf2f(v2 & 0xffff), cc2, a0);
        a1 = fmaf(bf2f(v2 >> 16), cc2, a1);
        a0 = fmaf(bf2f(v3 & 0xffff), c3, a0);
        a1 = fmaf(bf2f(v3 >> 16), c3, a1);
    }
    for (; i < end; ++i) {
        int s0 = csr_src[i];
        float c0 = csr_coef[i];
        uint32 v0 = H2[(size_t)s0 * 64 + c2];
        a0 = fmaf(bf2f(v0 & 0xffff), c0, a0);
        a1 = fmaf(bf2f(v0 >> 16), c0, a1);
    }
    float2 b2 = ((const float2*)bias)[c2];
    a0 = fmaxf(a0 + b2.x, 0.f);
    a1 = fmaxf(a1 + b2.y, 0.f);
    ((uint32*)Out)[(size_t)n * 64 + c2] = (uint32)f2bf(a0) | ((uint32)f2bf(a1) << 16);
}

// ---------------- pooling: one wave per 32-node window, uint32 loads, flush on change ----
__global__ __launch_bounds__(256) void k_poolb(const ushort16* __restrict__ H,
                                               const int* __restrict__ batch,
                                               float* __restrict__ pooled, int N) {
    int wave = threadIdx.x >> 6;
    int lane = threadIdx.x & 63;
    int start = blockIdx.x * 128 + wave * 32;
    if (start >= N) return;
    int end = min(start + 32, N);
    const uint32* H2 = (const uint32*)H;
    int g = batch[start];
    float a0 = 0.f, a1 = 0.f;
    for (int n = start; n < end; ++n) {
        int gn = batch[n];
        if (gn != g) {  // wave-uniform branch (batch value identical across lanes)
            atomicAdd(&pooled[g * D + lane * 2 + 0], a0);
            atomicAdd(&pooled[g * D + lane * 2 + 1], a1);
            a0 = a1 = 0.f;
            g = gn;
        }
        uint32 v = H2[(size_t)n * 64 + lane];
        a0 += bf2f(v & 0xffff);
        a1 += bf2f(v >> 16);
    }
    atomicAdd(&pooled[g * D + lane * 2 + 0], a0);
    atomicAdd(&pooled[g * D + lane * 2 + 1], a1);
}

// ---------------- final linear ----------------
__global__ __launch_bounds__(64) void k_lin(const float* __restrict__ pooled,
                                            const float* __restrict__ Wlin,
                                            const float* __restrict__ blin,
                                            float* __restrict__ out, int G) {
    int g = blockIdx.x;
    int t = threadIdx.x;
    float p0 = pooled[g * D + t];
    float p1 = pooled[g * D + t + 64];
    float a0 = fmaf(p0, Wlin[t * 2 + 0], p1 * Wlin[(t + 64) * 2 + 0]);
    float a1 = fmaf(p0, Wlin[t * 2 + 1], p1 * Wlin[(t + 64) * 2 + 1]);
    for (int off = 32; off > 0; off >>= 1) {
        a0 += __shfl_down(a0, off);
        a1 += __shfl_down(a1, off);
    }
    if (t == 0) {
        out[g * 2 + 0] = a0 + blin[0];
        out[g * 2 + 1] = a1 + blin[1];
    }
}

extern "C" void kernel_launch(void* const* d_in, const int* in_sizes, int n_in,
                              void* d_out, int out_size, void* d_ws, size_t ws_size,
                              hipStream_t stream) {
    const float* x    = (const float*)d_in[0];
    const int*   edge = (const int*)d_in[1];
    const int*   batch= (const int*)d_in[2];
    const float* W1   = (const float*)d_in[3];
    const float* b1   = (const float*)d_in[4];
    const float* W2   = (const float*)d_in[5];
    const float* b2   = (const float*)d_in[6];
    const float* W3   = (const float*)d_in[7];
    const float* b3   = (const float*)d_in[8];
    const float* Wlin = (const float*)d_in[9];
    const float* blin = (const float*)d_in[10];
    float* out = (float*)d_out;

    int N = in_sizes[2];
    int E = in_sizes[1] / 2;
    int G = out_size / 2;
    const int* src = edge;
    const int* dst = edge + E;

    char* ws = (char*)d_ws;
    size_t off = 0;
    auto alloc = [&](size_t bytes) -> void* {
        void* p = ws + off;
        off += (bytes + 511) & ~(size_t)511;
        return p;
    };
    int*      degi     = (int*)     alloc((size_t)N * 4);
    float*    dinv     = (float*)   alloc((size_t)N * 4);
    int*      offsets  = (int*)     alloc((size_t)(N + 1) * 4);
    int*      cursor   = (int*)     alloc((size_t)N * 4);
    int*      csr_src  = (int*)     alloc((size_t)E * 4);
    float*    csr_coef = (float*)   alloc((size_t)E * 4);
    ushort16* bufA     = (ushort16*)alloc((size_t)N * D * 2);
    ushort16* bufB     = (ushort16*)alloc((size_t)N * D * 2);
    float*    pooled   = (float*)   alloc((size_t)G * D * 4);
    int*      blockSums= (int*)     alloc((size_t)1024 * 4);
    (void)ws_size; (void)n_in;

    hipMemsetAsync(degi, 0, (size_t)N * 4, stream);
    hipMemsetAsync(pooled, 0, (size_t)G * D * 4, stream);

    int SB = (N + SCHUNK - 1) / SCHUNK;  // scan blocks (98 for N=100000)
    k_degree<<<(E + 255) / 256, 256, 0, stream>>>(dst, E, degi);
    k_dinv<<<(N + 255) / 256, 256, 0, stream>>>(degi, dinv, N);
    k_scanA<<<SB, 256, 0, stream>>>(degi, blockSums, N);
    k_scanB<<<1, 1024, 0, stream>>>(blockSums, SB);
    k_scanC<<<SB, 256, 0, stream>>>(degi, blockSums, offsets, cursor, N, E);
    k_fill<<<(E + 255) / 256, 256, 0, stream>>>(src, dst, E, dinv, cursor, csr_src, csr_coef);

    int gb = (N + 63) / 64;
    int ab = (N + 3) / 4;
    k_gemm_f32in <<<gb, 256, 0, stream>>>(x,    W1, bufA, N);
    k_aggb       <<<ab, 256, 0, stream>>>(bufA, offsets, csr_src, csr_coef, dinv, b1, bufB, N);
    k_gemm_bf16in<<<gb, 256, 0, stream>>>(bufB, W2, bufA, N);
    k_aggb       <<<ab, 256, 0, stream>>>(bufA, offsets, csr_src, csr_coef, dinv, b2, bufB, N);
    k_gemm_bf16in<<<gb, 256, 0, stream>>>(bufB, W3, bufA, N);
    k_aggb       <<<ab, 256, 0, stream>>>(bufA, offsets, csr_src, csr_coef, dinv, b3, bufB, N);

    k_poolb<<<(N + 127) / 128, 256, 0, stream>>>(bufB, batch, pooled, N);
    k_lin  <<<G, 64, 0, stream>>>(pooled, Wlin, blin, out, G);
}

// Round 13
// 682.136 us; speedup vs baseline: 2.4511x; 1.0469x over previous
//
#include <hip/hip_runtime.h>
#include <hip/hip_bf16.h>

#define D 128
#define SCHUNK 1024  // elements per scan block

typedef unsigned int uint32;
typedef unsigned short ushort16;

__device__ inline float bf2f(uint32 u16) {
    uint32 v = u16 << 16;
    float f;
    __builtin_memcpy(&f, &v, 4);
    return f;
}
__device__ inline ushort16 f2bf(float f) {
    uint32 u;
    __builtin_memcpy(&u, &f, 4);
    u = (u + 0x7FFFu + ((u >> 16) & 1u)) >> 16;   // round-to-nearest-even
    return (ushort16)u;
}

// ---------------- degree histogram ----------------
__global__ void k_degree(const int* __restrict__ dst, int E, int* __restrict__ degi) {
    int i = blockIdx.x * blockDim.x + threadIdx.x;
    if (i < E) atomicAdd(&degi[dst[i]], 1);
}

__global__ void k_dinv(const int* __restrict__ degi, float* __restrict__ dinv, int N) {
    int i = blockIdx.x * blockDim.x + threadIdx.x;
    if (i < N) dinv[i] = rsqrtf((float)degi[i] + 1.0f);
}

// ---------------- multi-block exclusive scan: phase A (block partial sums) ----------------
__global__ __launch_bounds__(256) void k_scanA(const int* __restrict__ degi,
                                               int* __restrict__ blockSums, int N) {
    __shared__ int red[256];
    int b = blockIdx.x, t = threadIdx.x;
    int base = b * SCHUNK;
    const int4* d4 = (const int4*)(degi + base);
    int4 v = make_int4(0, 0, 0, 0);
    int idx = base + t * 4;
    if (idx + 3 < N) v = d4[t];
    else {
        if (idx + 0 < N) v.x = degi[idx + 0];
        if (idx + 1 < N) v.y = degi[idx + 1];
        if (idx + 2 < N) v.z = degi[idx + 2];
        if (idx + 3 < N) v.w = degi[idx + 3];
    }
    red[t] = v.x + v.y + v.z + v.w;
    __syncthreads();
    for (int off = 128; off > 0; off >>= 1) {
        if (t < off) red[t] += red[t + off];
        __syncthreads();
    }
    if (t == 0) blockSums[b] = red[0];
}

// ---------------- phase B: single block exclusive scan of B block sums (B<=1024) --------
__global__ __launch_bounds__(1024) void k_scanB(int* __restrict__ blockSums, int B) {
    __shared__ int sums[1024];
    int t = threadIdx.x;
    int v = (t < B) ? blockSums[t] : 0;
    sums[t] = v;
    __syncthreads();
    for (int off = 1; off < 1024; off <<= 1) {
        int u = (t >= off) ? sums[t - off] : 0;
        __syncthreads();
        sums[t] += u;
        __syncthreads();
    }
    if (t < B) blockSums[t] = sums[t] - v;  // exclusive block base
}

// ---------------- phase C: per-block scan + write offsets/cursor --------------------------
__global__ __launch_bounds__(256) void k_scanC(const int* __restrict__ degi,
                                               const int* __restrict__ blockSums,
                                               int* __restrict__ offsets,
                                               int* __restrict__ cursor, int N, int E) {
    __shared__ int sums[256];
    int b = blockIdx.x, t = threadIdx.x;
    int base = b * SCHUNK;
    const int4* d4 = (const int4*)(degi + base);
    int4 v = make_int4(0, 0, 0, 0);
    int idx = base + t * 4;
    if (idx + 3 < N) v = d4[t];
    else {
        if (idx + 0 < N) v.x = degi[idx + 0];
        if (idx + 1 < N) v.y = degi[idx + 1];
        if (idx + 2 < N) v.z = degi[idx + 2];
        if (idx + 3 < N) v.w = degi[idx + 3];
    }
    int loc = v.x + v.y + v.z + v.w;
    sums[t] = loc;
    __syncthreads();
    for (int off = 1; off < 256; off <<= 1) {
        int u = (t >= off) ? sums[t - off] : 0;
        __syncthreads();
        sums[t] += u;
        __syncthreads();
    }
    int run = sums[t] - loc + blockSums[b];
    int vals[4] = {v.x, v.y, v.z, v.w};
#pragma unroll
    for (int j = 0; j < 4; ++j) {
        int i2 = idx + j;
        if (i2 < N) { offsets[i2] = run; cursor[i2] = run; }
        run += vals[j];
    }
    if (b == 0 && t == 0) offsets[N] = E;  // total degree == E by construction
}

// ---------------- CSR fill: interleaved 8B entries (src, coef) — one line per edge -------
__global__ void k_fill(const int* __restrict__ src, const int* __restrict__ dst, int E,
                       const float* __restrict__ dinv, int* __restrict__ cursor,
                       int2* __restrict__ csr) {
    int i = blockIdx.x * blockDim.x + threadIdx.x;
    if (i < E) {
        int s = src[i], d = dst[i];
        int pos = atomicAdd(&cursor[d], 1);
        float cf = dinv[s] * dinv[d];
        int2 e;
        e.x = s;
        e.y = __float_as_int(cf);
        csr[pos] = e;
    }
}

// ---------------- GEMM (f32 input): H_bf16[N,128] = X[N,128] @ W[128,128] ----------------
__global__ __launch_bounds__(256) void k_gemm_f32in(const float* __restrict__ X,
                                                    const float* __restrict__ W,
                                                    ushort16* __restrict__ H, int N) {
    __shared__ float4 xs[64 * 32];
    int tid = threadIdx.x;
    int base = blockIdx.x * 64;
    const float4* X4 = (const float4*)X;
#pragma unroll
    for (int i = 0; i < 8; ++i) {
        int f4 = tid + i * 256;
        int row = base + (f4 >> 5);
        float4 v = make_float4(0.f, 0.f, 0.f, 0.f);
        if (row < N) v = X4[(size_t)base * 32 + f4];
        xs[f4] = v;
    }
    __syncthreads();

    int c4 = tid & 31;
    int r0 = (tid >> 5) * 8;
    float4 acc[8];
#pragma unroll
    for (int i = 0; i < 8; ++i) acc[i] = make_float4(0.f, 0.f, 0.f, 0.f);

    const float4* W4 = (const float4*)W;
#pragma unroll 2
    for (int k4 = 0; k4 < 32; ++k4) {
        float4 w0 = W4[(k4 * 4 + 0) * 32 + c4];
        float4 w1 = W4[(k4 * 4 + 1) * 32 + c4];
        float4 w2 = W4[(k4 * 4 + 2) * 32 + c4];
        float4 w3 = W4[(k4 * 4 + 3) * 32 + c4];
#pragma unroll
        for (int i = 0; i < 8; ++i) {
            float4 xv = xs[(r0 + i) * 32 + k4];
            acc[i].x = fmaf(xv.x, w0.x, acc[i].x);
            acc[i].y = fmaf(xv.x, w0.y, acc[i].y);
            acc[i].z = fmaf(xv.x, w0.z, acc[i].z);
            acc[i].w = fmaf(xv.x, w0.w, acc[i].w);
            acc[i].x = fmaf(xv.y, w1.x, acc[i].x);
            acc[i].y = fmaf(xv.y, w1.y, acc[i].y);
            acc[i].z = fmaf(xv.y, w1.z, acc[i].z);
            acc[i].w = fmaf(xv.y, w1.w, acc[i].w);
            acc[i].x = fmaf(xv.z, w2.x, acc[i].x);
            acc[i].y = fmaf(xv.z, w2.y, acc[i].y);
            acc[i].z = fmaf(xv.z, w2.z, acc[i].z);
            acc[i].w = fmaf(xv.z, w2.w, acc[i].w);
            acc[i].x = fmaf(xv.w, w3.x, acc[i].x);
            acc[i].y = fmaf(xv.w, w3.y, acc[i].y);
            acc[i].z = fmaf(xv.w, w3.z, acc[i].z);
            acc[i].w = fmaf(xv.w, w3.w, acc[i].w);
        }
    }
#pragma unroll
    for (int i = 0; i < 8; ++i) {
        int row = base + r0 + i;
        if (row < N) {
            ushort4 o;
            o.x = f2bf(acc[i].x); o.y = f2bf(acc[i].y);
            o.z = f2bf(acc[i].z); o.w = f2bf(acc[i].w);
            *(ushort4*)&H[(size_t)row * D + c4 * 4] = o;
        }
    }
}

// ---------------- GEMM (bf16 input): H_bf16 = A_bf16 @ W ----------------
__global__ __launch_bounds__(256) void k_gemm_bf16in(const ushort16* __restrict__ A,
                                                     const float* __restrict__ W,
                                                     ushort16* __restrict__ H, int N) {
    __shared__ float4 xs[64 * 32];
    int tid = threadIdx.x;
    int base = blockIdx.x * 64;
    const uint4* A4 = (const uint4*)A;  // 16 uint4 per 128-bf16 row
#pragma unroll
    for (int i = 0; i < 4; ++i) {
        int u = tid + i * 256;          // [0,1024): row = u>>4, seg = u&15
        int row = base + (u >> 4);
        uint4 v = make_uint4(0, 0, 0, 0);
        if (row < N) v = A4[(size_t)base * 16 + u];
        float4 lo = make_float4(bf2f(v.x & 0xffff), bf2f(v.x >> 16),
                                bf2f(v.y & 0xffff), bf2f(v.y >> 16));
        float4 hi = make_float4(bf2f(v.z & 0xffff), bf2f(v.z >> 16),
                                bf2f(v.w & 0xffff), bf2f(v.w >> 16));
        int r = u >> 4, sgm = u & 15;
        xs[r * 32 + sgm * 2 + 0] = lo;
        xs[r * 32 + sgm * 2 + 1] = hi;
    }
    __syncthreads();

    int c4 = tid & 31;
    int r0 = (tid >> 5) * 8;
    float4 acc[8];
#pragma unroll
    for (int i = 0; i < 8; ++i) acc[i] = make_float4(0.f, 0.f, 0.f, 0.f);

    const float4* W4 = (const float4*)W;
#pragma unroll 2
    for (int k4 = 0; k4 < 32; ++k4) {
        float4 w0 = W4[(k4 * 4 + 0) * 32 + c4];
        float4 w1 = W4[(k4 * 4 + 1) * 32 + c4];
        float4 w2 = W4[(k4 * 4 + 2) * 32 + c4];
        float4 w3 = W4[(k4 * 4 + 3) * 32 + c4];
#pragma unroll
        for (int i = 0; i < 8; ++i) {
            float4 xv = xs[(r0 + i) * 32 + k4];
            acc[i].x = fmaf(xv.x, w0.x, acc[i].x);
            acc[i].y = fmaf(xv.x, w0.y, acc[i].y);
            acc[i].z = fmaf(xv.x, w0.z, acc[i].z);
            acc[i].w = fmaf(xv.x, w0.w, acc[i].w);
            acc[i].x = fmaf(xv.y, w1.x, acc[i].x);
            acc[i].y = fmaf(xv.y, w1.y, acc[i].y);
            acc[i].z = fmaf(xv.y, w1.z, acc[i].z);
            acc[i].w = fmaf(xv.y, w1.w, acc[i].w);
            acc[i].x = fmaf(xv.z, w2.x, acc[i].x);
            acc[i].y = fmaf(xv.z, w2.y, acc[i].y);
            acc[i].z = fmaf(xv.z, w2.z, acc[i].z);
            acc[i].w = fmaf(xv.z, w2.w, acc[i].w);
            acc[i].x = fmaf(xv.w, w3.x, acc[i].x);
            acc[i].y = fmaf(xv.w, w3.y, acc[i].y);
            acc[i].z = fmaf(xv.w, w3.z, acc[i].z);
            acc[i].w = fmaf(xv.w, w3.w, acc[i].w);
        }
    }
#pragma unroll
    for (int i = 0; i < 8; ++i) {
        int row = base + r0 + i;
        if (row < N) {
            ushort4 o;
            o.x = f2bf(acc[i].x); o.y = f2bf(acc[i].y);
            o.z = f2bf(acc[i].z); o.w = f2bf(acc[i].w);
            *(ushort4*)&H[(size_t)row * D + c4 * 4] = o;
        }
    }
}

// ---------------- aggregation (bf16 H): Out = relu(norm-agg(H) + b), bf16 out ----------
// 64 lanes per node, 2 features/lane; edge loop unrolled x4 (4 gathers in flight)
__global__ __launch_bounds__(256) void k_aggb(const ushort16* __restrict__ H,
                                              const int* __restrict__ offsets,
                                              const int2* __restrict__ csr,
                                              const float* __restrict__ dinv,
                                              const float* __restrict__ bias,
                                              ushort16* __restrict__ Out, int N) {
    int n = blockIdx.x * 4 + (threadIdx.x >> 6);
    int c2 = threadIdx.x & 63;
    if (n >= N) return;
    const uint32* H2 = (const uint32*)H;
    float dn = dinv[n];
    float dn2 = dn * dn;
    uint32 self = H2[(size_t)n * 64 + c2];
    float a0 = bf2f(self & 0xffff) * dn2;
    float a1 = bf2f(self >> 16) * dn2;
    int beg = offsets[n], end = offsets[n + 1];
    int i = beg;
    for (; i + 4 <= end; i += 4) {
        int2 e0 = csr[i + 0], e1 = csr[i + 1];
        int2 e2 = csr[i + 2], e3 = csr[i + 3];
        uint32 v0 = H2[(size_t)e0.x * 64 + c2];
        uint32 v1 = H2[(size_t)e1.x * 64 + c2];
        uint32 v2 = H2[(size_t)e2.x * 64 + c2];
        uint32 v3 = H2[(size_t)e3.x * 64 + c2];
        float c0 = __int_as_float(e0.y), c1 = __int_as_float(e1.y);
        float cc2 = __int_as_float(e2.y), c3 = __int_as_float(e3.y);
        a0 = fmaf(bf2f(v0 & 0xffff), c0, a0);
        a1 = fmaf(bf2f(v0 >> 16), c0, a1);
        a0 = fmaf(bf2f(v1 & 0xffff), c1, a0);
        a1 = fmaf(bf2f(v1 >> 16), c1, a1);
        a0 = fmaf(bf2f(v2 & 0xffff), cc2, a0);
        a1 = fmaf(bf2f(v2 >> 16), cc2, a1);
        a0 = fmaf(bf2f(v3 & 0xffff), c3, a0);
        a1 = fmaf(bf2f(v3 >> 16), c3, a1);
    }
    for (; i < end; ++i) {
        int2 e0 = csr[i];
        float c0 = __int_as_float(e0.y);
        uint32 v0 = H2[(size_t)e0.x * 64 + c2];
        a0 = fmaf(bf2f(v0 & 0xffff), c0, a0);
        a1 = fmaf(bf2f(v0 >> 16), c0, a1);
    }
    float2 b2 = ((const float2*)bias)[c2];
    a0 = fmaxf(a0 + b2.x, 0.f);
    a1 = fmaxf(a1 + b2.y, 0.f);
    ((uint32*)Out)[(size_t)n * 64 + c2] = (uint32)f2bf(a0) | ((uint32)f2bf(a1) << 16);
}

// ---------------- pooling: one wave per 32-node window, uint32 loads, flush on change ----
__global__ __launch_bounds__(256) void k_poolb(const ushort16* __restrict__ H,
                                               const int* __restrict__ batch,
                                               float* __restrict__ pooled, int N) {
    int wave = threadIdx.x >> 6;
    int lane = threadIdx.x & 63;
    int start = blockIdx.x * 128 + wave * 32;
    if (start >= N) return;
    int end = min(start + 32, N);
    const uint32* H2 = (const uint32*)H;
    int g = batch[start];
    float a0 = 0.f, a1 = 0.f;
    for (int n = start; n < end; ++n) {
        int gn = batch[n];
        if (gn != g) {  // wave-uniform branch (batch value identical across lanes)
            atomicAdd(&pooled[g * D + lane * 2 + 0], a0);
            atomicAdd(&pooled[g * D + lane * 2 + 1], a1);
            a0 = a1 = 0.f;
            g = gn;
        }
        uint32 v = H2[(size_t)n * 64 + lane];
        a0 += bf2f(v & 0xffff);
        a1 += bf2f(v >> 16);
    }
    atomicAdd(&pooled[g * D + lane * 2 + 0], a0);
    atomicAdd(&pooled[g * D + lane * 2 + 1], a1);
}

// ---------------- final linear ----------------
__global__ __launch_bounds__(64) void k_lin(const float* __restrict__ pooled,
                                            const float* __restrict__ Wlin,
                                            const float* __restrict__ blin,
                                            float* __restrict__ out, int G) {
    int g = blockIdx.x;
    int t = threadIdx.x;
    float p0 = pooled[g * D + t];
    float p1 = pooled[g * D + t + 64];
    float a0 = fmaf(p0, Wlin[t * 2 + 0], p1 * Wlin[(t + 64) * 2 + 0]);
    float a1 = fmaf(p0, Wlin[t * 2 + 1], p1 * Wlin[(t + 64) * 2 + 1]);
    for (int off = 32; off > 0; off >>= 1) {
        a0 += __shfl_down(a0, off);
        a1 += __shfl_down(a1, off);
    }
    if (t == 0) {
        out[g * 2 + 0] = a0 + blin[0];
        out[g * 2 + 1] = a1 + blin[1];
    }
}

extern "C" void kernel_launch(void* const* d_in, const int* in_sizes, int n_in,
                              void* d_out, int out_size, void* d_ws, size_t ws_size,
                              hipStream_t stream) {
    const float* x    = (const float*)d_in[0];
    const int*   edge = (const int*)d_in[1];
    const int*   batch= (const int*)d_in[2];
    const float* W1   = (const float*)d_in[3];
    const float* b1   = (const float*)d_in[4];
    const float* W2   = (const float*)d_in[5];
    const float* b2   = (const float*)d_in[6];
    const float* W3   = (const float*)d_in[7];
    const float* b3   = (const float*)d_in[8];
    const float* Wlin = (const float*)d_in[9];
    const float* blin = (const float*)d_in[10];
    float* out = (float*)d_out;

    int N = in_sizes[2];
    int E = in_sizes[1] / 2;
    int G = out_size / 2;
    const int* src = edge;
    const int* dst = edge + E;

    char* ws = (char*)d_ws;
    size_t off = 0;
    auto alloc = [&](size_t bytes) -> void* {
        void* p = ws + off;
        off += (bytes + 511) & ~(size_t)511;
        return p;
    };
    int*      degi     = (int*)     alloc((size_t)N * 4);
    float*    dinv     = (float*)   alloc((size_t)N * 4);
    int*      offsets  = (int*)     alloc((size_t)(N + 1) * 4);
    int*      cursor   = (int*)     alloc((size_t)N * 4);
    int2*     csr      = (int2*)    alloc((size_t)E * 8);
    ushort16* bufA     = (ushort16*)alloc((size_t)N * D * 2);
    ushort16* bufB     = (ushort16*)alloc((size_t)N * D * 2);
    float*    pooled   = (float*)   alloc((size_t)G * D * 4);
    int*      blockSums= (int*)     alloc((size_t)1024 * 4);
    (void)ws_size; (void)n_in;

    hipMemsetAsync(degi, 0, (size_t)N * 4, stream);
    hipMemsetAsync(pooled, 0, (size_t)G * D * 4, stream);

    int SB = (N + SCHUNK - 1) / SCHUNK;  // scan blocks (98 for N=100000)
    k_degree<<<(E + 255) / 256, 256, 0, stream>>>(dst, E, degi);
    k_dinv<<<(N + 255) / 256, 256, 0, stream>>>(degi, dinv, N);
    k_scanA<<<SB, 256, 0, stream>>>(degi, blockSums, N);
    k_scanB<<<1, 1024, 0, stream>>>(blockSums, SB);
    k_scanC<<<SB, 256, 0, stream>>>(degi, blockSums, offsets, cursor, N, E);
    k_fill<<<(E + 255) / 256, 256, 0, stream>>>(src, dst, E, dinv, cursor, csr);

    int gb = (N + 63) / 64;
    int ab = (N + 3) / 4;
    k_gemm_f32in <<<gb, 256, 0, stream>>>(x,    W1, bufA, N);
    k_aggb       <<<ab, 256, 0, stream>>>(bufA, offsets, csr, dinv, b1, bufB, N);
    k_gemm_bf16in<<<gb, 256, 0, stream>>>(bufB, W2, bufA, N);
    k_aggb       <<<ab, 256, 0, stream>>>(bufA, offsets, csr, dinv, b2, bufB, N);
    k_gemm_bf16in<<<gb, 256, 0, stream>>>(bufB, W3, bufA, N);
    k_aggb       <<<ab, 256, 0, stream>>>(bufA, offsets, csr, dinv, b3, bufB, N);

    k_poolb<<<(N + 127) / 128, 256, 0, stream>>>(bufB, batch, pooled, N);
    k_lin  <<<G, 64, 0, stream>>>(pooled, Wlin, blin, out, G);
}